// Round 7
// baseline (144.417 us; speedup 1.0000x reference)
//
#include <hip/hip_runtime.h>

#define LN_EPS 1e-5f

constexpr int Bn = 4, Nn = 256, Dn = 256, Hn = 256;

// ws layout (floats):
//   aA  @ 0        (1024*256)
//   bB  @ 262144   (1024*256)
//   rC  @ 524288   (1028)  -- atomic accumulators: r[b,h] (1024) + C[b] (4)
//                             zeroed by gemm block (0,0)

// Device-wide barrier state (module globals: loaded as 0, and the exit
// protocol below returns them to 0 at the end of every kernel_launch call,
// so graph replays see identical state).
__device__ unsigned g_bar = 0;
__device__ unsigned g_exit = 0;

// ---------------------------------------------------------------------------
// Kernel 1: aA[m,h] = x[m,:]@Wg[:D,h] + bg[h]  (half=0)
//           bB[m,h] = x[m,:]@Wg[D:,h]          (half=1)
// Unchanged from round 6 (proven). Block (0,0) zeroes rC (1028 floats).
// ---------------------------------------------------------------------------
__global__ __launch_bounds__(512) void gemm_ab_kernel(
    const float* __restrict__ x, const float* __restrict__ Wg,
    const float* __restrict__ bg, float* __restrict__ aA,
    float* __restrict__ bB, float* __restrict__ rC)
{
    int mt = blockIdx.x;     // 0..255
    int half = blockIdx.y;   // 0 -> a, 1 -> b
    int m0 = mt * 4;
    int t = threadIdx.x;

    if (mt == 0 && half == 0) {
        for (int k = t; k < 1028; k += 512) rC[k] = 0.0f;
    }

    __shared__ float xs[4][256];
    __shared__ float accP[8][4][256];

    if (t < 256)
        reinterpret_cast<float4*>(&xs[0][0])[t] =
            reinterpret_cast<const float4*>(x + m0 * Dn)[t];
    __syncthreads();

    int h4 = t & 63;
    int dc = t >> 6;         // wave-uniform
    const float* Wp = Wg + (half ? Dn * Hn : 0) + h4 * 4;

    float4 acc[4];
#pragma unroll
    for (int m = 0; m < 4; ++m) acc[m] = make_float4(0.f, 0.f, 0.f, 0.f);

#pragma unroll 4
    for (int dd = 0; dd < 32; ++dd) {
        int d = dc * 32 + dd;
        float4 w = *reinterpret_cast<const float4*>(Wp + d * Hn);
#pragma unroll
        for (int m = 0; m < 4; ++m) {
            float xv = xs[m][d];
            acc[m].x = fmaf(xv, w.x, acc[m].x);
            acc[m].y = fmaf(xv, w.y, acc[m].y);
            acc[m].z = fmaf(xv, w.z, acc[m].z);
            acc[m].w = fmaf(xv, w.w, acc[m].w);
        }
    }
#pragma unroll
    for (int m = 0; m < 4; ++m)
        *reinterpret_cast<float4*>(&accP[dc][m][h4 * 4]) = acc[m];
    __syncthreads();

    int h = t & 255;
    int mh = t >> 8;
    float binit = half ? 0.0f : bg[h];
    float* outp = half ? bB : aA;
#pragma unroll
    for (int mi = 0; mi < 2; ++mi) {
        int m = mh * 2 + mi;
        float v = binit;
#pragma unroll
        for (int c = 0; c < 8; ++c) v += accP[c][m][h];
        outp[(m0 + m) * Hn + h] = v;
    }
}

// ---------------------------------------------------------------------------
// Kernel 2: FUSED pair -> device barrier -> finish+add.
// Grid 512 x 512 threads, __launch_bounds__(512,4) => 2 blocks/CU guaranteed
// resident (all 512 co-resident; LDS 44KB allows 3/CU) -- required for the
// atomic spin barrier.
// Pair phase: identical structure to round 6 (single pass over bB, stats
//   from staging registers, LDS tile, prefetch). C partial folded into
//   rC[1024+b] via atomicAdd (device-scope, coherent).
// Barrier: g_bar arrive+spin, release/acquire threadfences; exit-counter
//   protocol resets {g_bar,g_exit} to 0 after all blocks have passed.
// Finish phase (all 512 blocks, redundant GEMV per block):
//   rs = gg*(r+C)+N^2*gb; y = relu(rs@Wf+bf); rel = LN(y);
//   each block writes its 2-row slice of out = rel + x.
// ---------------------------------------------------------------------------
__global__ __launch_bounds__(512, 4) void fused_pf_kernel(
    const float* __restrict__ aA, const float* __restrict__ bB,
    const float* __restrict__ x,
    const float* __restrict__ gg, const float* __restrict__ gb,
    const float* __restrict__ Wf, const float* __restrict__ bfv,
    const float* __restrict__ fg, const float* __restrict__ fb,
    float* __restrict__ rC, float* __restrict__ out)
{
    const int b  = blockIdx.x >> 7;
    const int i0 = (blockIdx.x & 127) * 2;
    const int t  = threadIdx.x;

    __shared__ float Bs[32][260];
    __shared__ float invL[2][32];
    __shared__ float wred[8];
    // finish-phase LDS
    __shared__ float rs[256];
    __shared__ float relS[256];
    __shared__ float ysum[8][260];
    __shared__ float pS[4], pQ[4];
    __shared__ float cbuf;

    const int jg = t >> 4;
    const int p  = t & 15;
    const int h4 = t & 63;
    const int c  = t >> 6;    // wave-uniform

    // ================= pair phase =================
    {
        const float* aArow0 = aA + (b * Nn + i0) * Hn;
        const float* aArow1 = aArow0 + Hn;

        float4 As0[4], As1[4];
#pragma unroll
        for (int r = 0; r < 4; ++r) {
            As0[r] = *reinterpret_cast<const float4*>(aArow0 + 4 * (p + 16 * r));
            As1[r] = *reinterpret_cast<const float4*>(aArow1 + 4 * (p + 16 * r));
        }
        const float4 a0 = *reinterpret_cast<const float4*>(aArow0 + h4 * 4);
        const float4 a1 = *reinterpret_cast<const float4*>(aArow1 + h4 * 4);

        const float* browbase = bB + b * Nn * Hn;

        float4 acc0 = make_float4(0.f, 0.f, 0.f, 0.f);
        float4 acc1 = make_float4(0.f, 0.f, 0.f, 0.f);
        float Csum = 0.f;

        float4 bv[4], bvn[4];
        {
            const float* rp = browbase + jg * Hn;
#pragma unroll
            for (int r = 0; r < 4; ++r)
                bv[r] = *reinterpret_cast<const float4*>(rp + 4 * (p + 16 * r));
        }

        for (int jt = 0; jt < 8; ++jt) {
            float s0 = 0.f, q0 = 0.f, s1 = 0.f, q1 = 0.f;
#pragma unroll
            for (int r = 0; r < 4; ++r) {
                float v;
                v = fmaxf(As0[r].x + bv[r].x, 0.f); s0 += v; q0 = fmaf(v, v, q0);
                v = fmaxf(As0[r].y + bv[r].y, 0.f); s0 += v; q0 = fmaf(v, v, q0);
                v = fmaxf(As0[r].z + bv[r].z, 0.f); s0 += v; q0 = fmaf(v, v, q0);
                v = fmaxf(As0[r].w + bv[r].w, 0.f); s0 += v; q0 = fmaf(v, v, q0);
                v = fmaxf(As1[r].x + bv[r].x, 0.f); s1 += v; q1 = fmaf(v, v, q1);
                v = fmaxf(As1[r].y + bv[r].y, 0.f); s1 += v; q1 = fmaf(v, v, q1);
                v = fmaxf(As1[r].z + bv[r].z, 0.f); s1 += v; q1 = fmaf(v, v, q1);
                v = fmaxf(As1[r].w + bv[r].w, 0.f); s1 += v; q1 = fmaf(v, v, q1);
            }
#pragma unroll
            for (int r = 0; r < 4; ++r)
                *reinterpret_cast<float4*>(&Bs[jg][4 * (p + 16 * r)]) = bv[r];
            if (jt < 7) {
                const float* rp = browbase + ((jt + 1) * 32 + jg) * Hn;
#pragma unroll
                for (int r = 0; r < 4; ++r)
                    bvn[r] = *reinterpret_cast<const float4*>(rp + 4 * (p + 16 * r));
            }
#pragma unroll
            for (int off = 8; off >= 1; off >>= 1) {
                s0 += __shfl_xor(s0, off, 16);
                q0 += __shfl_xor(q0, off, 16);
                s1 += __shfl_xor(s1, off, 16);
                q1 += __shfl_xor(q1, off, 16);
            }
            if (p == 0) {
                float m0 = s0 * (1.f / 256.f), m1 = s1 * (1.f / 256.f);
                float inv0 = rsqrtf(q0 * (1.f / 256.f) - m0 * m0 + LN_EPS);
                float inv1 = rsqrtf(q1 * (1.f / 256.f) - m1 * m1 + LN_EPS);
                invL[0][jg] = inv0;
                invL[1][jg] = inv1;
                Csum -= m0 * inv0 + m1 * inv1;
            }
            __syncthreads();
#pragma unroll
            for (int jj = 0; jj < 4; ++jj) {
                int j = c * 4 + jj;
                float w0 = invL[0][j];
                float w1 = invL[1][j];
                float4 b4 = *reinterpret_cast<const float4*>(&Bs[j][h4 * 4]);
                acc0.x = fmaf(w0, fmaxf(a0.x + b4.x, 0.f), acc0.x);
                acc0.y = fmaf(w0, fmaxf(a0.y + b4.y, 0.f), acc0.y);
                acc0.z = fmaf(w0, fmaxf(a0.z + b4.z, 0.f), acc0.z);
                acc0.w = fmaf(w0, fmaxf(a0.w + b4.w, 0.f), acc0.w);
                acc1.x = fmaf(w1, fmaxf(a1.x + b4.x, 0.f), acc1.x);
                acc1.y = fmaf(w1, fmaxf(a1.y + b4.y, 0.f), acc1.y);
                acc1.z = fmaf(w1, fmaxf(a1.z + b4.z, 0.f), acc1.z);
                acc1.w = fmaf(w1, fmaxf(a1.w + b4.w, 0.f), acc1.w);
            }
            __syncthreads();
#pragma unroll
            for (int r = 0; r < 4; ++r) bv[r] = bvn[r];
        }

        // combine: red aliases Bs
        float* red = &Bs[0][0];
        *reinterpret_cast<float4*>(red + c * 256 + h4 * 4) = acc0;
        *reinterpret_cast<float4*>(red + (8 + c) * 256 + h4 * 4) = acc1;

        float cs = Csum;
#pragma unroll
        for (int off = 32; off >= 1; off >>= 1) cs += __shfl_xor(cs, off, 64);
        if ((t & 63) == 0) wred[t >> 6] = cs;
        __syncthreads();

        if (t < 256) {
            float v = 0.f;
#pragma unroll
            for (int cc = 0; cc < 8; ++cc)
                v += red[cc * 256 + t] + red[(8 + cc) * 256 + t];
            atomicAdd(&rC[b * Hn + t], v);
        }
        if (t == 0) {
            float cb = 0.f;
#pragma unroll
            for (int w = 0; w < 8; ++w) cb += wred[w];
            atomicAdd(&rC[1024 + b], cb);
        }
    }

    // ================= device-wide barrier =================
    __syncthreads();
    if (t == 0) {
        __threadfence();                       // release
        atomicAdd(&g_bar, 1u);
        while (atomicAdd(&g_bar, 0u) < 512u) __builtin_amdgcn_s_sleep(8);
        __threadfence();                       // acquire
        unsigned e = atomicAdd(&g_exit, 1u);
        if (e == 511u) {                       // last block through: reset
            atomicExch(&g_bar, 0u);
            atomicExch(&g_exit, 0u);
        }
    }
    __syncthreads();

    // ================= finish + add phase (all 512 blocks) =================
    float rraw = 0.f;
    if (t == 0) cbuf = atomicAdd(&rC[1024 + b], 0.0f);   // atomic load
    if (t < 256) rraw = atomicAdd(&rC[b * Hn + t], 0.0f); // atomic load
    __syncthreads();
    if (t < 256) rs[t] = gg[t] * (rraw + cbuf) + 65536.0f * gb[t];
    __syncthreads();

    {
        const int kc = t >> 6;   // 0..7, 32 k each
        float4 acc = make_float4(0.f, 0.f, 0.f, 0.f);
        const float* Wp = Wf + h4 * 4;
#pragma unroll 8
        for (int kk = 0; kk < 32; ++kk) {
            int k = kc * 32 + kk;
            float4 w = *reinterpret_cast<const float4*>(Wp + k * Hn);
            float rv = rs[k];
            acc.x = fmaf(rv, w.x, acc.x);
            acc.y = fmaf(rv, w.y, acc.y);
            acc.z = fmaf(rv, w.z, acc.z);
            acc.w = fmaf(rv, w.w, acc.w);
        }
        *reinterpret_cast<float4*>(&ysum[kc][h4 * 4]) = acc;
    }
    __syncthreads();

    float v = 0.f;
    if (t < 256) {
        v = bfv[t];
#pragma unroll
        for (int cc = 0; cc < 8; ++cc) v += ysum[cc][t];
        v = fmaxf(v, 0.f);
    }
    {
        float sv = (t < 256) ? v : 0.f;
        float qv = (t < 256) ? v * v : 0.f;
#pragma unroll
        for (int off = 32; off >= 1; off >>= 1) {
            sv += __shfl_xor(sv, off, 64);
            qv += __shfl_xor(qv, off, 64);
        }
        if (t < 256 && (t & 63) == 0) { pS[t >> 6] = sv; pQ[t >> 6] = qv; }
    }
    __syncthreads();

    if (t < 256) {
        float S = pS[0] + pS[1] + pS[2] + pS[3];
        float Q = pQ[0] + pQ[1] + pQ[2] + pQ[3];
        float m = S * (1.f / 256.f);
        float inv = rsqrtf(Q * (1.f / 256.f) - m * m + LN_EPS);
        relS[t] = (v - m) * inv * fg[t] + fb[t];
    }
    __syncthreads();

    if (t < 128) {
        int nsl = blockIdx.x & 127;            // 2 n-rows per block
        int row = nsl * 2 + (t >> 6);
        int col4 = t & 63;
        int idx = (b * Nn + row) * (Hn / 4) + col4;
        float4 xv = reinterpret_cast<const float4*>(x)[idx];
        float4 r4 = *reinterpret_cast<const float4*>(&relS[col4 * 4]);
        float4 o;
        o.x = xv.x + r4.x;
        o.y = xv.y + r4.y;
        o.z = xv.z + r4.z;
        o.w = xv.w + r4.w;
        reinterpret_cast<float4*>(out)[idx] = o;
    }
}

// ---------------------------------------------------------------------------
extern "C" void kernel_launch(void* const* d_in, const int* in_sizes, int n_in,
                              void* d_out, int out_size, void* d_ws, size_t ws_size,
                              hipStream_t stream)
{
    const float* x   = (const float*)d_in[0];
    const float* Wg  = (const float*)d_in[1];
    const float* bg  = (const float*)d_in[2];
    const float* gg  = (const float*)d_in[3];
    const float* gb  = (const float*)d_in[4];
    const float* Wf  = (const float*)d_in[5];
    const float* bfv = (const float*)d_in[6];
    const float* fg  = (const float*)d_in[7];
    const float* fb  = (const float*)d_in[8];
    float* out = (float*)d_out;

    float* ws = (float*)d_ws;
    float* aA = ws;                 // 1024*256
    float* bB = ws + 262144;        // 1024*256
    float* rC = ws + 524288;        // 1024 r + 4 C

    gemm_ab_kernel<<<dim3(256, 2), 512, 0, stream>>>(x, Wg, bg, aA, bB, rC);
    fused_pf_kernel<<<512, 512, 0, stream>>>(aA, bB, x, gg, gb, Wf, bfv,
                                             fg, fb, rC, out);
}

// Round 8
// 103.198 us; speedup vs baseline: 1.3994x; 1.3994x over previous
//
#include <hip/hip_runtime.h>

#define LN_EPS 1e-5f

constexpr int Bn = 4, Nn = 256, Dn = 256, Hn = 256;

// ws layout (floats):
//   aA    @ 0        (1024*256)
//   bB    @ 262144   (1024*256)
//   rC    @ 524288   (1024)      -- atomic accumulators r[b,h], zeroed in gemm
//   Cpart @ 525312   (512)       -- per-pair-block C partials (no contention)
//   rel   @ 525824   (1024)

// ---------------------------------------------------------------------------
// Kernel 1: aA[m,h] = x[m,:]@Wg[:D,h] + bg[h]  (half=0)
//           bB[m,h] = x[m,:]@Wg[D:,h]          (half=1)
// Block: 4-row m-tile, 512 threads = (h4 in [0,64), dc in [0,8)).
// float4 W loads (1KB/wave coalesced). Block (0,0) zeroes rC.
// ---------------------------------------------------------------------------
__global__ __launch_bounds__(512) void gemm_ab_kernel(
    const float* __restrict__ x, const float* __restrict__ Wg,
    const float* __restrict__ bg, float* __restrict__ aA,
    float* __restrict__ bB, float* __restrict__ rC)
{
    int mt = blockIdx.x;     // 0..255
    int half = blockIdx.y;   // 0 -> a, 1 -> b
    int m0 = mt * 4;
    int t = threadIdx.x;

    if (mt == 0 && half == 0) {
        for (int k = t; k < 1024; k += 512) rC[k] = 0.0f;
    }

    __shared__ float xs[4][256];
    __shared__ float accP[8][4][256];

    if (t < 256)
        reinterpret_cast<float4*>(&xs[0][0])[t] =
            reinterpret_cast<const float4*>(x + m0 * Dn)[t];
    __syncthreads();

    int h4 = t & 63;
    int dc = t >> 6;         // wave-uniform
    const float* Wp = Wg + (half ? Dn * Hn : 0) + h4 * 4;

    float4 acc[4];
#pragma unroll
    for (int m = 0; m < 4; ++m) acc[m] = make_float4(0.f, 0.f, 0.f, 0.f);

#pragma unroll 4
    for (int dd = 0; dd < 32; ++dd) {
        int d = dc * 32 + dd;
        float4 w = *reinterpret_cast<const float4*>(Wp + d * Hn);
#pragma unroll
        for (int m = 0; m < 4; ++m) {
            float xv = xs[m][d];
            acc[m].x = fmaf(xv, w.x, acc[m].x);
            acc[m].y = fmaf(xv, w.y, acc[m].y);
            acc[m].z = fmaf(xv, w.z, acc[m].z);
            acc[m].w = fmaf(xv, w.w, acc[m].w);
        }
    }
#pragma unroll
    for (int m = 0; m < 4; ++m)
        *reinterpret_cast<float4*>(&accP[dc][m][h4 * 4]) = acc[m];
    __syncthreads();

    int h = t & 255;
    int mh = t >> 8;
    float binit = half ? 0.0f : bg[h];
    float* outp = half ? bB : aA;
#pragma unroll
    for (int mi = 0; mi < 2; ++mi) {
        int m = mh * 2 + mi;
        float v = binit;
#pragma unroll
        for (int c = 0; c < 8; ++c) v += accP[c][m][h];
        outp[(m0 + m) * Hn + h] = v;
    }
}

// ---------------------------------------------------------------------------
// Kernel 2: fused pair block, single pass over bB, DOUBLE-BUFFERED LDS.
// Block = (b, 2 i-rows), 512 threads, grid 512 (2 blocks/CU; LDS 67KB).
// Per j-tile (32 rows): ONE barrier per tile (was two):
//   stats(k) from staging regs -> Bs[k&1]/invL[k&1] writes -> prefetch k+1
//   -> 16-lane shuffle reduce -> sync -> phase2(k) reads Bs[k&1].
// WAR on Bs[k&1] only at stats(k+2), which is after sync(k+1) => safe.
// End: LDS combine (red aliases Bs[0] -- safe: last phase2 uses Bs[1]),
// 1 atomic/h; Cpart[block] (no contention).
// ---------------------------------------------------------------------------
__global__ __launch_bounds__(512, 2) void pair_kernel(
    const float* __restrict__ aA, const float* __restrict__ bB,
    float* __restrict__ rC, float* __restrict__ Cpart)
{
    const int b  = blockIdx.x >> 7;
    const int i0 = (blockIdx.x & 127) * 2;
    const int t  = threadIdx.x;

    __shared__ float Bs[2][32][260];
    __shared__ float invL[2][2][32];
    __shared__ float wred[8];

    const int jg = t >> 4;
    const int p  = t & 15;
    const int h4 = t & 63;
    const int c  = t >> 6;    // wave-uniform

    const float* aArow0 = aA + (b * Nn + i0) * Hn;
    const float* aArow1 = aArow0 + Hn;

    // stats-mapping A fragments: h = 4*(p+16r)+{0..3}
    float4 As0[4], As1[4];
#pragma unroll
    for (int r = 0; r < 4; ++r) {
        As0[r] = *reinterpret_cast<const float4*>(aArow0 + 4 * (p + 16 * r));
        As1[r] = *reinterpret_cast<const float4*>(aArow1 + 4 * (p + 16 * r));
    }
    // phase2-mapping A fragments: h = h4*4+{0..3}
    const float4 a0 = *reinterpret_cast<const float4*>(aArow0 + h4 * 4);
    const float4 a1 = *reinterpret_cast<const float4*>(aArow1 + h4 * 4);

    const float* browbase = bB + b * Nn * Hn;

    float4 acc0 = make_float4(0.f, 0.f, 0.f, 0.f);
    float4 acc1 = make_float4(0.f, 0.f, 0.f, 0.f);
    float Csum = 0.f;

    float4 bv[4], bvn[4];
    {
        const float* rp = browbase + jg * Hn;
#pragma unroll
        for (int r = 0; r < 4; ++r)
            bv[r] = *reinterpret_cast<const float4*>(rp + 4 * (p + 16 * r));
    }

    for (int jt = 0; jt < 8; ++jt) {
        const int kb = jt & 1;
        // ---- stats from staging registers ----
        float s0 = 0.f, q0 = 0.f, s1 = 0.f, q1 = 0.f;
#pragma unroll
        for (int r = 0; r < 4; ++r) {
            float v;
            v = fmaxf(As0[r].x + bv[r].x, 0.f); s0 += v; q0 = fmaf(v, v, q0);
            v = fmaxf(As0[r].y + bv[r].y, 0.f); s0 += v; q0 = fmaf(v, v, q0);
            v = fmaxf(As0[r].z + bv[r].z, 0.f); s0 += v; q0 = fmaf(v, v, q0);
            v = fmaxf(As0[r].w + bv[r].w, 0.f); s0 += v; q0 = fmaf(v, v, q0);
            v = fmaxf(As1[r].x + bv[r].x, 0.f); s1 += v; q1 = fmaf(v, v, q1);
            v = fmaxf(As1[r].y + bv[r].y, 0.f); s1 += v; q1 = fmaf(v, v, q1);
            v = fmaxf(As1[r].z + bv[r].z, 0.f); s1 += v; q1 = fmaf(v, v, q1);
            v = fmaxf(As1[r].w + bv[r].w, 0.f); s1 += v; q1 = fmaf(v, v, q1);
        }
        // ---- stage to LDS (ping-pong buffer) ----
#pragma unroll
        for (int r = 0; r < 4; ++r)
            *reinterpret_cast<float4*>(&Bs[kb][jg][4 * (p + 16 * r)]) = bv[r];
        // ---- prefetch next tile ----
        if (jt < 7) {
            const float* rp = browbase + ((jt + 1) * 32 + jg) * Hn;
#pragma unroll
            for (int r = 0; r < 4; ++r)
                bvn[r] = *reinterpret_cast<const float4*>(rp + 4 * (p + 16 * r));
        }
        // ---- 16-lane reduce -> inv ----
#pragma unroll
        for (int off = 8; off >= 1; off >>= 1) {
            s0 += __shfl_xor(s0, off, 16);
            q0 += __shfl_xor(q0, off, 16);
            s1 += __shfl_xor(s1, off, 16);
            q1 += __shfl_xor(q1, off, 16);
        }
        if (p == 0) {
            float m0 = s0 * (1.f / 256.f), m1 = s1 * (1.f / 256.f);
            float inv0 = rsqrtf(q0 * (1.f / 256.f) - m0 * m0 + LN_EPS);
            float inv1 = rsqrtf(q1 * (1.f / 256.f) - m1 * m1 + LN_EPS);
            invL[kb][0][jg] = inv0;
            invL[kb][1][jg] = inv1;
            Csum -= m0 * inv0 + m1 * inv1;
        }
        __syncthreads();          // the ONLY barrier per tile
        // ---- phase 2: weighted accumulate from LDS ----
        {
            const float4 w0v = *reinterpret_cast<const float4*>(&invL[kb][0][c * 4]);
            const float4 w1v = *reinterpret_cast<const float4*>(&invL[kb][1][c * 4]);
            const float w0a[4] = {w0v.x, w0v.y, w0v.z, w0v.w};
            const float w1a[4] = {w1v.x, w1v.y, w1v.z, w1v.w};
#pragma unroll
            for (int jj = 0; jj < 4; ++jj) {
                int j = c * 4 + jj;
                float w0 = w0a[jj];
                float w1 = w1a[jj];
                float4 b4 = *reinterpret_cast<const float4*>(&Bs[kb][j][h4 * 4]);
                acc0.x = fmaf(w0, fmaxf(a0.x + b4.x, 0.f), acc0.x);
                acc0.y = fmaf(w0, fmaxf(a0.y + b4.y, 0.f), acc0.y);
                acc0.z = fmaf(w0, fmaxf(a0.z + b4.z, 0.f), acc0.z);
                acc0.w = fmaf(w0, fmaxf(a0.w + b4.w, 0.f), acc0.w);
                acc1.x = fmaf(w1, fmaxf(a1.x + b4.x, 0.f), acc1.x);
                acc1.y = fmaf(w1, fmaxf(a1.y + b4.y, 0.f), acc1.y);
                acc1.z = fmaf(w1, fmaxf(a1.z + b4.z, 0.f), acc1.z);
                acc1.w = fmaf(w1, fmaxf(a1.w + b4.w, 0.f), acc1.w);
            }
        }
        if (jt < 7) {
#pragma unroll
            for (int r = 0; r < 4; ++r) bv[r] = bvn[r];
        }
    }

    // ---- combine: red aliases Bs[0] (last phase2 read Bs[1]; any wave
    //      still in phase2(7) touches only Bs[1]/invL[1] -> safe) ----
    float* red = &Bs[0][0][0];   // red[(i*8+c)*256 + h], 4096 floats
    *reinterpret_cast<float4*>(red + c * 256 + h4 * 4) = acc0;
    *reinterpret_cast<float4*>(red + (8 + c) * 256 + h4 * 4) = acc1;

    float cs = Csum;
#pragma unroll
    for (int off = 32; off >= 1; off >>= 1) cs += __shfl_xor(cs, off, 64);
    if ((t & 63) == 0) wred[t >> 6] = cs;
    __syncthreads();

    if (t < 256) {
        float v = 0.f;
#pragma unroll
        for (int cc = 0; cc < 8; ++cc)
            v += red[cc * 256 + t] + red[(8 + cc) * 256 + t];
        atomicAdd(&rC[b * Hn + t], v);
    }
    if (t == 0) {
        float cb = 0.f;
#pragma unroll
        for (int w = 0; w < 8; ++w) cb += wred[w];
        Cpart[blockIdx.x] = cb;
    }
}

// ---------------------------------------------------------------------------
// Kernel 3: per-batch finish. 4 blocks x 512 threads.
//   Cb = sum of 128 Cpart; rs[h] = gg[h]*(r[b,h]+Cb) + N^2*gb[h]
//   y = relu(rs@Wf + bf); rel = LN(y) (divisor 256)
// ---------------------------------------------------------------------------
__global__ __launch_bounds__(512) void finish_kernel(
    const float* __restrict__ rC, const float* __restrict__ Cpart,
    const float* __restrict__ gg, const float* __restrict__ gb,
    const float* __restrict__ Wf, const float* __restrict__ bfv,
    const float* __restrict__ fg, const float* __restrict__ fb,
    float* __restrict__ rel)
{
    const int b = blockIdx.x;
    const int t = threadIdx.x;
    __shared__ float rs[256];
    __shared__ float ysum[8][260];
    __shared__ float cred[2];
    __shared__ float pS[4], pQ[4];

    float cv = (t < 128) ? Cpart[b * 128 + t] : 0.f;
#pragma unroll
    for (int off = 32; off >= 1; off >>= 1) cv += __shfl_xor(cv, off, 64);
    if (t == 0 || t == 64) cred[t >> 6] = cv;
    __syncthreads();

    if (t < 256) {
        float Cb = cred[0] + cred[1];
        rs[t] = gg[t] * (rC[b * Hn + t] + Cb) + 65536.0f * gb[t];
    }
    __syncthreads();

    const int h4 = t & 63;
    const int kc = t >> 6;   // 0..7, 32 k each
    float4 acc = make_float4(0.f, 0.f, 0.f, 0.f);
    const float* Wp = Wf + h4 * 4;
#pragma unroll 8
    for (int kk = 0; kk < 32; ++kk) {
        int k = kc * 32 + kk;
        float4 w = *reinterpret_cast<const float4*>(Wp + k * Hn);
        float rv = rs[k];
        acc.x = fmaf(rv, w.x, acc.x);
        acc.y = fmaf(rv, w.y, acc.y);
        acc.z = fmaf(rv, w.z, acc.z);
        acc.w = fmaf(rv, w.w, acc.w);
    }
    *reinterpret_cast<float4*>(&ysum[kc][h4 * 4]) = acc;
    __syncthreads();

    float v = 0.f;
    if (t < 256) {
        v = bfv[t];
#pragma unroll
        for (int c = 0; c < 8; ++c) v += ysum[c][t];
        v = fmaxf(v, 0.f);
    }
    float sv = (t < 256) ? v : 0.f;
    float qv = (t < 256) ? v * v : 0.f;
#pragma unroll
    for (int off = 32; off >= 1; off >>= 1) {
        sv += __shfl_xor(sv, off, 64);
        qv += __shfl_xor(qv, off, 64);
    }
    if (t < 256 && (t & 63) == 0) { pS[t >> 6] = sv; pQ[t >> 6] = qv; }
    __syncthreads();

    if (t < 256) {
        float S = pS[0] + pS[1] + pS[2] + pS[3];
        float Q = pQ[0] + pQ[1] + pQ[2] + pQ[3];
        float m = S * (1.f / 256.f);
        float inv = rsqrtf(Q * (1.f / 256.f) - m * m + LN_EPS);
        rel[b * Hn + t] = (v - m) * inv * fg[t] + fb[t];
    }
}

// ---------------------------------------------------------------------------
// Kernel 4: out[b,n,d] = rel[b,d] + x[b,n,d], float4-vectorized.
// ---------------------------------------------------------------------------
__global__ __launch_bounds__(256) void add_kernel(
    const float* __restrict__ rel, const float* __restrict__ x,
    float* __restrict__ out)
{
    int idx = blockIdx.x * blockDim.x + threadIdx.x;   // float4 units
    int b = idx >> 14;
    int d4 = idx & 63;
    float4 r4 = reinterpret_cast<const float4*>(rel)[b * 64 + d4];
    float4 x4 = reinterpret_cast<const float4*>(x)[idx];
    float4 o;
    o.x = r4.x + x4.x;
    o.y = r4.y + x4.y;
    o.z = r4.z + x4.z;
    o.w = r4.w + x4.w;
    reinterpret_cast<float4*>(out)[idx] = o;
}

// ---------------------------------------------------------------------------
extern "C" void kernel_launch(void* const* d_in, const int* in_sizes, int n_in,
                              void* d_out, int out_size, void* d_ws, size_t ws_size,
                              hipStream_t stream)
{
    const float* x   = (const float*)d_in[0];
    const float* Wg  = (const float*)d_in[1];
    const float* bg  = (const float*)d_in[2];
    const float* gg  = (const float*)d_in[3];
    const float* gb  = (const float*)d_in[4];
    const float* Wf  = (const float*)d_in[5];
    const float* bfv = (const float*)d_in[6];
    const float* fg  = (const float*)d_in[7];
    const float* fb  = (const float*)d_in[8];
    float* out = (float*)d_out;

    float* ws    = (float*)d_ws;
    float* aA    = ws;                 // 1024*256
    float* bB    = ws + 262144;        // 1024*256
    float* rC    = ws + 524288;        // 1024
    float* Cpart = ws + 525312;        // 512
    float* rel   = ws + 525824;        // 1024

    gemm_ab_kernel<<<dim3(256, 2), 512, 0, stream>>>(x, Wg, bg, aA, bB, rC);
    pair_kernel<<<512, 512, 0, stream>>>(aA, bB, rC, Cpart);
    finish_kernel<<<4, 512, 0, stream>>>(rC, Cpart, gg, gb, Wf, bfv, fg, fb, rel);
    add_kernel<<<256, 256, 0, stream>>>(rel, x, out);
}